// Round 1
// baseline (130.318 us; speedup 1.0000x reference)
//
#include <hip/hip_runtime.h>

#define B   2
#define C   256
#define CM  64     // compressed channels
#define CE  100    // encoder out channels
#define H   40
#define W   40
#define HW  1600
#define KK  25     // K*K

// ---------------------------------------------------------------------------
// K0: transpose w_enc (100 oc x 64 ic x 9) into scalar-load-friendly layout
// wT[row][32] where row = ((ocq*4+icq)*16+icl)*9 + tap and wT[row][ol] holds
// the weight for output channel ocq*25+ol. Reads fully coalesced.
// ---------------------------------------------------------------------------
__global__ __launch_bounds__(256) void k0_wt(const float* __restrict__ w,
                                             float* __restrict__ wT) {
  int idx = blockIdx.x * 256 + threadIdx.x;   // over 100*576 = 57600
  if (idx < 57600) {
    int row = idx / 576, col = idx - row * 576;  // col = (icq*16+icl)*9+tap
    int ocq = row / 25, ol = row - ocq * 25;
    wT[((size_t)(ocq * 576 + col)) * 32 + ol] = w[idx];
  }
}

// ---------------------------------------------------------------------------
// K1: 1x1 conv 256 -> 64 as LDS GEMM, K(=x channels) split 4-way over blocks.
// grid (25 px-tiles, 4 K-quarters, 2 b), block 256 = 16 ty(oc) x 16 tx(px),
// thread tile 4 oc x 4 px. Output: fp32 partials pc[ich][b][64][1600].
// ---------------------------------------------------------------------------
__global__ __launch_bounds__(256) void k1_conv1x1(
    const float* __restrict__ x, const float* __restrict__ w,
    float* __restrict__ pc) {
  const int t = blockIdx.x, ich = blockIdx.y, b = blockIdx.z;
  __shared__ __align__(16) float xs[64 * 64];    // 16 KB [icl][px]
  __shared__ __align__(16) float wsA[64 * 64];   // 16 KB [icl][oc] (transposed)
  const int tid = threadIdx.x;

  const float4* x4 = (const float4*)(x + ((size_t)b * C + ich * 64) * HW + t * 64);
#pragma unroll
  for (int i = 0; i < 4; i++) {
    int idx = tid + i * 256;                     // icl = idx>>4, q = idx&15
    ((float4*)xs)[idx] = x4[(idx >> 4) * 400 + (idx & 15)];
  }
  const float4* w4 = (const float4*)w;
#pragma unroll
  for (int i = 0; i < 4; i++) {
    int idx = tid + i * 256;
    int icq = idx >> 6, oc = idx & 63;           // icq 0..15
    float4 f = w4[oc * 64 + ich * 16 + icq];
    wsA[(icq * 4 + 0) * 64 + oc] = f.x;
    wsA[(icq * 4 + 1) * 64 + oc] = f.y;
    wsA[(icq * 4 + 2) * 64 + oc] = f.z;
    wsA[(icq * 4 + 3) * 64 + oc] = f.w;
  }
  __syncthreads();

  const int ty = tid >> 4, tx = tid & 15;
  float acc[4][4];
#pragma unroll
  for (int i = 0; i < 4; i++)
#pragma unroll
    for (int j = 0; j < 4; j++) acc[i][j] = 0.f;

#pragma unroll 4
  for (int icl = 0; icl < 64; icl++) {
    float4 a = *(const float4*)&wsA[icl * 64 + ty * 4];
    float4 bb = *(const float4*)&xs[icl * 64 + tx * 4];
    float av[4] = {a.x, a.y, a.z, a.w};
    float bv[4] = {bb.x, bb.y, bb.z, bb.w};
#pragma unroll
    for (int i = 0; i < 4; i++)
#pragma unroll
      for (int j = 0; j < 4; j++) acc[i][j] += av[i] * bv[j];
  }

  float* o = pc + ((size_t)ich * B + b) * CM * HW + t * 64 + tx * 4;
#pragma unroll
  for (int j = 0; j < 4; j++)
    *(float4*)&o[(size_t)(ty * 4 + j) * HW] =
        make_float4(acc[j][0], acc[j][1], acc[j][2], acc[j][3]);
}

// ---------------------------------------------------------------------------
// K2: 3x3 conv 64 -> 100, pad 1.  grid (50 tiles of 8x4 px, 4 ocq, 4 icq)
// = 800 blocks (3.1/CU). Lane = (bb, 8x4 px); 4 waves k-split 16 ic (4 each).
// Weights come from wT via wave-uniform scalar loads (s_load on the SMEM
// pipe) -> LDS inner loop is a single ds_read_b32 per tap. Cross-wave
// tree-reduce via aliased LDS. Writes encP[icq][b][100][1600].
// ---------------------------------------------------------------------------
__global__ __launch_bounds__(256) void k2_conv3x3(
    const float* __restrict__ pc, const float* __restrict__ wT,
    float* __restrict__ encP) {
  const int t = blockIdx.x, ocq = blockIdx.y, icq = blockIdx.z;
  const int ty = t / 10, tx = t - ty * 10;       // tile origin (ty*8, tx*4)
  __shared__ __align__(16) float smem[3200];     // 12.8 KB
  float* cs   = smem;    // [bb2][icl16][10*6 halo] = 1920 floats
  float* pacc = smem;    // alias for reduction (3200 floats)
  const int tid = threadIdx.x;

  // ---- stage cs: comp halo = sum of 4 fp32 K-partials
  for (int i = tid; i < 1920; i += 256) {
    int bb = i / 960, r = i - bb * 960;
    int icl = r / 60, rr = r - icl * 60;
    int yy = rr / 6, xx = rr - yy * 6;
    int gy = ty * 8 + yy - 1, gx = tx * 4 + xx - 1;
    float v = 0.f;
    if (gy >= 0 && gy < H && gx >= 0 && gx < W) {
      int o = bb * 102400 + (icq * 16 + icl) * HW + gy * W + gx;
      v = pc[o] + pc[204800 + o] + pc[409600 + o] + pc[614400 + o];
    }
    cs[i] = v;
  }
  __syncthreads();

  const int wv = tid >> 6, lane = tid & 63;
  const int bb = lane >> 5, py = (lane & 31) >> 2, px = lane & 3;
  float acc[25];
#pragma unroll
  for (int j = 0; j < 25; j++) acc[j] = 0.f;

  const float* wbase0 = wT + (size_t)((ocq * 4 + icq) * 16) * 288;  // *9*32

#pragma unroll
  for (int t4 = 0; t4 < 4; t4++) {
    // force the ic index into an SGPR so weight addresses are wave-uniform
    const int icl = __builtin_amdgcn_readfirstlane(wv * 4 + t4);
    const float* c0 = &cs[(bb * 16 + icl) * 60 + py * 6 + px];
    const float* wrow = wbase0 + icl * 288;
#pragma unroll
    for (int dy = 0; dy < 3; dy++)
#pragma unroll
      for (int dx = 0; dx < 3; dx++) {
        const float xv = c0[dy * 6 + dx];
        const float* wq = wrow + (dy * 3 + dx) * 32;
#pragma unroll
        for (int j = 0; j < 25; j++) acc[j] = fmaf(xv, wq[j], acc[j]);
      }
  }

  // ---- cross-wave reduction (waves hold different ic slices)
  __syncthreads();                       // everyone done reading cs
  if (wv == 1 || wv == 3) {
    const int slot = wv >> 1;
#pragma unroll
    for (int j = 0; j < 25; j++) pacc[(slot * 25 + j) * 64 + lane] = acc[j];
  }
  __syncthreads();
  if (wv == 0 || wv == 2) {
    const int slot = wv >> 1;
#pragma unroll
    for (int j = 0; j < 25; j++) acc[j] += pacc[(slot * 25 + j) * 64 + lane];
  }
  __syncthreads();
  if (wv == 2) {
#pragma unroll
    for (int j = 0; j < 25; j++) pacc[j * 64 + lane] = acc[j];
  }
  __syncthreads();
  if (wv == 0) {
    const int base_px = (ty * 8 + py) * W + tx * 4 + px;
#pragma unroll
    for (int ol = 0; ol < 25; ol++)
      encP[(((size_t)icq * 2 + bb) * CE + ocq * 25 + ol) * HW + base_px] =
          acc[ol] + pacc[ol * 64 + lane];
  }
}

// ---------------------------------------------------------------------------
// K3: softmax over 25 (summing 4 enc partials) + reassembly.
// grid (40 i0, 10 jq of 4 cols, 2 b) = 800 blocks; block covers ALL 256
// channels (4 ch/thread -> one b128 weight broadcast feeds 16 FMAs; softmax
// computed once per pixel instead of 4x). LDS 42.6 KB -> 3 blocks/CU.
// ---------------------------------------------------------------------------
__global__ __launch_bounds__(256) void k3_reassemble(
    const float* __restrict__ x, const float* __restrict__ encP,
    float* __restrict__ out) {
  const int i0 = blockIdx.x;
  const int jq = blockIdx.y;
  const int b  = blockIdx.z;
  const int tid = threadIdx.x;

  __shared__ __align__(16) float xsm[5 * 8 * 256];   // 40 KB [ki][cc][ch]
  __shared__ __align__(16) float wlds[4 * KK * 4];   // 1.6 KB [j0l][k][d]

  // ---- softmax for the block's 4 columns x 4 sub-pixels (16 threads)
  if (tid < 16) {
    const int j0l = tid >> 2, d = tid & 3;
    const int j0 = jq * 4 + j0l;
    const int t20 = (j0 >= 20) ? 1 : 0;
    const int off = 2 * t20 + (d & 1);
    const int col = (j0 - 20 * t20) * 2 + (d >> 1);
    const float* ep = encP + (size_t)b * CE * HW + i0 * W + col;
    float v[KK];
    float m = -1e30f;
#pragma unroll
    for (int k = 0; k < KK; k++) {
      int o = (k * 4 + off) * HW;
      v[k] = ep[o] + ep[320000 + o] + ep[640000 + o] + ep[960000 + o];
      m = fmaxf(m, v[k]);
    }
    float s = 0.f;
#pragma unroll
    for (int k = 0; k < KK; k++) {
      v[k] = expf(v[k] - m);
      s += v[k];
    }
    const float inv = 1.f / s;
#pragma unroll
    for (int k = 0; k < KK; k++) wlds[(j0l * KK + k) * 4 + d] = v[k] * inv;
  }

  // ---- stage x halo: 5 rows x 8 cols x 256 ch, ch contiguous in LDS
  {
    const float* xb = x + ((size_t)b * C + tid) * HW;
    const int gx0 = jq * 4 - 2;
#pragma unroll
    for (int ki = 0; ki < 5; ki++) {
      const int gy = i0 - 2 + ki;
      const bool rowok = (gy >= 0) && (gy < H);
#pragma unroll
      for (int cc = 0; cc < 8; cc++) {
        const int gx = gx0 + cc;
        float v = 0.f;
        if (rowok && gx >= 0 && gx < W) v = xb[gy * W + gx];
        xsm[(ki * 8 + cc) * 256 + tid] = v;
      }
    }
  }
  __syncthreads();

  const int wv = tid >> 6, lane = tid & 63, ch0 = lane * 4;
  float4 a0 = make_float4(0.f, 0.f, 0.f, 0.f);
  float4 a1 = a0, a2 = a0, a3 = a0;

#pragma unroll
  for (int ki = 0; ki < 5; ki++)
#pragma unroll
    for (int kj = 0; kj < 5; kj++) {
      float4 xv = *(const float4*)&xsm[(ki * 8 + wv + kj) * 256 + ch0];
      float4 w4 = *(const float4*)&wlds[(wv * KK + ki * 5 + kj) * 4];
      a0.x += xv.x * w4.x; a0.y += xv.y * w4.x; a0.z += xv.z * w4.x; a0.w += xv.w * w4.x;
      a1.x += xv.x * w4.y; a1.y += xv.y * w4.y; a1.z += xv.z * w4.y; a1.w += xv.w * w4.y;
      a2.x += xv.x * w4.z; a2.y += xv.y * w4.z; a2.z += xv.z * w4.z; a2.w += xv.w * w4.z;
      a3.x += xv.x * w4.w; a3.y += xv.y * w4.w; a3.z += xv.z * w4.w; a3.w += xv.w * w4.w;
    }

  const int j0 = jq * 4 + wv;
  float* ob = out + ((size_t)b * C + ch0) * 6400 + i0 * 160 + j0 * 4;
  *(float4*)&ob[0]     = make_float4(a0.x, a1.x, a2.x, a3.x);
  *(float4*)&ob[6400]  = make_float4(a0.y, a1.y, a2.y, a3.y);
  *(float4*)&ob[12800] = make_float4(a0.z, a1.z, a2.z, a3.z);
  *(float4*)&ob[19200] = make_float4(a0.w, a1.w, a2.w, a3.w);
}

// ---------------------------------------------------------------------------
extern "C" void kernel_launch(void* const* d_in, const int* in_sizes, int n_in,
                              void* d_out, int out_size, void* d_ws, size_t ws_size,
                              hipStream_t stream) {
  const float* x      = (const float*)d_in[0];
  const float* w_comp = (const float*)d_in[1];
  const float* w_enc  = (const float*)d_in[2];
  float* out = (float*)d_out;

  float* pc   = (float*)d_ws;                        // 4*2*64*1600*4  = 3,276,800 B
  float* encP = (float*)((char*)d_ws + 3276800);     // 4*2*100*1600*4 = 5,120,000 B
  float* wT   = (float*)((char*)d_ws + 8396800);     // 2304*32*4      =   294,912 B

  k0_wt<<<dim3(225), 256, 0, stream>>>(w_enc, wT);
  k1_conv1x1<<<dim3(25, 4, B), 256, 0, stream>>>(x, w_comp, pc);
  k2_conv3x3<<<dim3(50, 4, 4), 256, 0, stream>>>(pc, wT, encP);
  k3_reassemble<<<dim3(40, 10, B), 256, 0, stream>>>(x, encP, out);
}

// Round 2
// 129.944 us; speedup vs baseline: 1.0029x; 1.0029x over previous
//
#include <hip/hip_runtime.h>

#define B   2
#define C   256
#define CM  64     // compressed channels
#define CE  100    // encoder out channels
#define H   40
#define W   40
#define HW  1600
#define KK  25     // K*K

// ---------------------------------------------------------------------------
// K0: prep kernel. Blocks 0..511: zero-pad x -> xpad[b][c][44][48].
// Blocks 512..736: transpose w_enc into wT[((ocq*4+icq)*16+icl)*9+tap][32]
// (scalar-load-friendly layout for k2).
// ---------------------------------------------------------------------------
__global__ __launch_bounds__(256) void k0_prep(
    const float* __restrict__ x, const float* __restrict__ w,
    float* __restrict__ xpad, float* __restrict__ wT) {
  const int bid = blockIdx.x;
  if (bid < 512) {                       // pad one (b,c) plane
    const float* src = x + (size_t)bid * HW;
    float* dst = xpad + (size_t)bid * (44 * 48);
    for (int i = threadIdx.x; i < 44 * 48; i += 256) {
      int py = i / 48, px = i - py * 48;
      int gy = py - 2, gx = px - 2;
      float v = 0.f;
      if (gy >= 0 && gy < H && gx >= 0 && gx < W) v = src[gy * W + gx];
      dst[i] = v;
    }
  } else {                               // weight transpose (57600 elements)
    int idx = (bid - 512) * 256 + threadIdx.x;
    if (idx < 57600) {
      int row = idx / 576, col = idx - row * 576;  // col = (icq*16+icl)*9+tap
      int ocq = row / 25, ol = row - ocq * 25;
      wT[((size_t)(ocq * 576 + col)) * 32 + ol] = w[idx];
    }
  }
}

// ---------------------------------------------------------------------------
// K1: 1x1 conv 256 -> 64 as LDS GEMM, K(=x channels) split 4-way over blocks.
// grid (25 px-tiles, 4 K-quarters, 2 b), block 256 = 16 ty(oc) x 16 tx(px),
// thread tile 4 oc x 4 px. Output: fp32 partials pc[ich][b][64][1600].
// ---------------------------------------------------------------------------
__global__ __launch_bounds__(256) void k1_conv1x1(
    const float* __restrict__ x, const float* __restrict__ w,
    float* __restrict__ pc) {
  const int t = blockIdx.x, ich = blockIdx.y, b = blockIdx.z;
  __shared__ __align__(16) float xs[64 * 64];    // 16 KB [icl][px]
  __shared__ __align__(16) float wsA[64 * 64];   // 16 KB [icl][oc] (transposed)
  const int tid = threadIdx.x;

  const float4* x4 = (const float4*)(x + ((size_t)b * C + ich * 64) * HW + t * 64);
#pragma unroll
  for (int i = 0; i < 4; i++) {
    int idx = tid + i * 256;                     // icl = idx>>4, q = idx&15
    ((float4*)xs)[idx] = x4[(idx >> 4) * 400 + (idx & 15)];
  }
  const float4* w4 = (const float4*)w;
#pragma unroll
  for (int i = 0; i < 4; i++) {
    int idx = tid + i * 256;
    int icq = idx >> 6, oc = idx & 63;           // icq 0..15
    float4 f = w4[oc * 64 + ich * 16 + icq];
    wsA[(icq * 4 + 0) * 64 + oc] = f.x;
    wsA[(icq * 4 + 1) * 64 + oc] = f.y;
    wsA[(icq * 4 + 2) * 64 + oc] = f.z;
    wsA[(icq * 4 + 3) * 64 + oc] = f.w;
  }
  __syncthreads();

  const int ty = tid >> 4, tx = tid & 15;
  float acc[4][4];
#pragma unroll
  for (int i = 0; i < 4; i++)
#pragma unroll
    for (int j = 0; j < 4; j++) acc[i][j] = 0.f;

#pragma unroll 4
  for (int icl = 0; icl < 64; icl++) {
    float4 a = *(const float4*)&wsA[icl * 64 + ty * 4];
    float4 bb = *(const float4*)&xs[icl * 64 + tx * 4];
    float av[4] = {a.x, a.y, a.z, a.w};
    float bv[4] = {bb.x, bb.y, bb.z, bb.w};
#pragma unroll
    for (int i = 0; i < 4; i++)
#pragma unroll
      for (int j = 0; j < 4; j++) acc[i][j] += av[i] * bv[j];
  }

  float* o = pc + ((size_t)ich * B + b) * CM * HW + t * 64 + tx * 4;
#pragma unroll
  for (int j = 0; j < 4; j++)
    *(float4*)&o[(size_t)(ty * 4 + j) * HW] =
        make_float4(acc[j][0], acc[j][1], acc[j][2], acc[j][3]);
}

// ---------------------------------------------------------------------------
// K2: 3x3 conv 64 -> 100, pad 1.  grid (50 tiles of 8x4 px, 4 ocq, 4 icq)
// = 800 blocks (3.1/CU). Lane = (bb, 8x4 px); 4 waves k-split 16 ic (4 each).
// Weights come from wT via wave-uniform scalar loads -> LDS inner loop is a
// single ds_read_b32 per tap. Cross-wave tree-reduce via aliased LDS.
// ---------------------------------------------------------------------------
__global__ __launch_bounds__(256) void k2_conv3x3(
    const float* __restrict__ pc, const float* __restrict__ wT,
    float* __restrict__ encP) {
  const int t = blockIdx.x, ocq = blockIdx.y, icq = blockIdx.z;
  const int ty = t / 10, tx = t - ty * 10;       // tile origin (ty*8, tx*4)
  __shared__ __align__(16) float smem[3200];     // 12.8 KB
  float* cs   = smem;    // [bb2][icl16][10*6 halo] = 1920 floats
  float* pacc = smem;    // alias for reduction (3200 floats)
  const int tid = threadIdx.x;

  // ---- stage cs: comp halo = sum of 4 fp32 K-partials
  for (int i = tid; i < 1920; i += 256) {
    int bb = i / 960, r = i - bb * 960;
    int icl = r / 60, rr = r - icl * 60;
    int yy = rr / 6, xx = rr - yy * 6;
    int gy = ty * 8 + yy - 1, gx = tx * 4 + xx - 1;
    float v = 0.f;
    if (gy >= 0 && gy < H && gx >= 0 && gx < W) {
      int o = bb * 102400 + (icq * 16 + icl) * HW + gy * W + gx;
      v = pc[o] + pc[204800 + o] + pc[409600 + o] + pc[614400 + o];
    }
    cs[i] = v;
  }
  __syncthreads();

  const int wv = tid >> 6, lane = tid & 63;
  const int bb = lane >> 5, py = (lane & 31) >> 2, px = lane & 3;
  float acc[25];
#pragma unroll
  for (int j = 0; j < 25; j++) acc[j] = 0.f;

  const float* wbase0 = wT + (size_t)((ocq * 4 + icq) * 16) * 288;  // *9*32

#pragma unroll
  for (int t4 = 0; t4 < 4; t4++) {
    const int icl = __builtin_amdgcn_readfirstlane(wv * 4 + t4);
    const float* c0 = &cs[(bb * 16 + icl) * 60 + py * 6 + px];
    const float* wrow = wbase0 + icl * 288;
#pragma unroll
    for (int dy = 0; dy < 3; dy++)
#pragma unroll
      for (int dx = 0; dx < 3; dx++) {
        const float xv = c0[dy * 6 + dx];
        const float* wq = wrow + (dy * 3 + dx) * 32;
#pragma unroll
        for (int j = 0; j < 25; j++) acc[j] = fmaf(xv, wq[j], acc[j]);
      }
  }

  // ---- cross-wave reduction (waves hold different ic slices)
  __syncthreads();
  if (wv == 1 || wv == 3) {
    const int slot = wv >> 1;
#pragma unroll
    for (int j = 0; j < 25; j++) pacc[(slot * 25 + j) * 64 + lane] = acc[j];
  }
  __syncthreads();
  if (wv == 0 || wv == 2) {
    const int slot = wv >> 1;
#pragma unroll
    for (int j = 0; j < 25; j++) acc[j] += pacc[(slot * 25 + j) * 64 + lane];
  }
  __syncthreads();
  if (wv == 2) {
#pragma unroll
    for (int j = 0; j < 25; j++) pacc[j * 64 + lane] = acc[j];
  }
  __syncthreads();
  if (wv == 0) {
    const int base_px = (ty * 8 + py) * W + tx * 4 + px;
#pragma unroll
    for (int ol = 0; ol < 25; ol++)
      encP[(((size_t)icq * 2 + bb) * CE + ocq * 25 + ol) * HW + base_px] =
          acc[ol] + pacc[ol * 64 + lane];
  }
}

// ---------------------------------------------------------------------------
// K2b: softmax over 25 (summing 4 enc partials), coalesced.
// grid (40 i0, 2 b), 192 threads (160 active). Thread = (off 0..3, col 0..39)
// -> consecutive threads read consecutive encP addresses (160B runs).
// Output wnorm[b][i0][j0][k*4+d] so k3 reads 400 contiguous floats per block.
// ---------------------------------------------------------------------------
__global__ __launch_bounds__(192) void k2b_softmax(
    const float* __restrict__ encP, float* __restrict__ wnorm) {
  const int i0 = blockIdx.x, b = blockIdx.y;
  __shared__ float tr[4000];                     // 16 KB
  const int tid = threadIdx.x;
  if (tid < 160) {
    const int off = tid / 40, col = tid - off * 40;
    const int j0 = (col >> 1) + 20 * (off >> 1);
    const int d  = ((col & 1) << 1) | (off & 1);
    const float* ep = encP + (size_t)b * 160000 + off * 1600 + i0 * 40 + col;
    float v[KK];
    float m = -1e30f;
#pragma unroll
    for (int k = 0; k < KK; k++) {
      int o = k * 6400;                          // (k*4)*HW
      float s = ep[o] + ep[320000 + o] + ep[640000 + o] + ep[960000 + o];
      v[k] = s;
      m = fmaxf(m, s);
    }
    float s = 0.f;
#pragma unroll
    for (int k = 0; k < KK; k++) {
      v[k] = expf(v[k] - m);
      s += v[k];
    }
    const float inv = 1.f / s;
#pragma unroll
    for (int k = 0; k < KK; k++) tr[j0 * 100 + k * 4 + d] = v[k] * inv;
  }
  __syncthreads();
  float* wb = wnorm + ((size_t)b * 40 + i0) * 4000;
  for (int i = tid; i < 4000; i += 192) wb[i] = tr[i];
}

// ---------------------------------------------------------------------------
// K3: reassembly. grid (40 i0, 10 jq, 2 b) = 800 blocks, block 256.
// LDS xsm[px 0..39][ch, stride 260] staged from xpad via coalesced dwordx4 +
// conflict-free b32 scatter (banks (px*4+c)%32 cover all 32 exactly 2x/wave).
// Weights: one coalesced 400-float load from wnorm. Compute: per tap one
// b128 x-read (conflict-free) + one b128 w-broadcast feeding 16 FMAs.
// ---------------------------------------------------------------------------
__global__ __launch_bounds__(256) void k3_reassemble(
    const float* __restrict__ xpad, const float* __restrict__ wnorm,
    float* __restrict__ out) {
  const int i0 = blockIdx.x;
  const int jq = blockIdx.y;
  const int b  = blockIdx.z;
  const int tid = threadIdx.x;

  __shared__ __align__(16) float xsm[40 * 260];  // 40.6 KB
  __shared__ __align__(16) float wlds[400];      // 1.6 KB [j0l*100 + k*4 + d]

  // ---- weights: 400 contiguous floats
  if (tid < 100) {
    const float4 w4 = *(const float4*)(
        wnorm + (((size_t)b * 40 + i0) * 40 + jq * 4) * 100 + tid * 4);
    *(float4*)&wlds[tid * 4] = w4;
  }

  // ---- x halo: 5 rows x 8 cols x 256 ch from padded x, no bounds checks
  {
    const float* xb = xpad + (size_t)b * 256 * (44 * 48) + i0 * 48 + jq * 4;
    const int f4 = tid & 1, cth = tid >> 1;      // cth 0..127
#pragma unroll
    for (int it = 0; it < 10; it++) {
      const int ki = (it < 5) ? it : it - 5;
      const int c  = (it < 5 ? 0 : 128) + cth;
      float4 v = *(const float4*)(xb + ((size_t)c * 44 + ki) * 48 + f4 * 4);
      const int px = ki * 8 + f4 * 4;
      xsm[(px + 0) * 260 + c] = v.x;
      xsm[(px + 1) * 260 + c] = v.y;
      xsm[(px + 2) * 260 + c] = v.z;
      xsm[(px + 3) * 260 + c] = v.w;
    }
  }
  __syncthreads();

  const int wv = tid >> 6, lane = tid & 63, ch0 = lane * 4;
  float4 a0 = make_float4(0.f, 0.f, 0.f, 0.f);
  float4 a1 = a0, a2 = a0, a3 = a0;

#pragma unroll
  for (int ki = 0; ki < 5; ki++)
#pragma unroll
    for (int kj = 0; kj < 5; kj++) {
      float4 xv = *(const float4*)&xsm[(ki * 8 + wv + kj) * 260 + ch0];
      float4 w4 = *(const float4*)&wlds[wv * 100 + (ki * 5 + kj) * 4];
      a0.x += xv.x * w4.x; a0.y += xv.y * w4.x; a0.z += xv.z * w4.x; a0.w += xv.w * w4.x;
      a1.x += xv.x * w4.y; a1.y += xv.y * w4.y; a1.z += xv.z * w4.y; a1.w += xv.w * w4.y;
      a2.x += xv.x * w4.z; a2.y += xv.y * w4.z; a2.z += xv.z * w4.z; a2.w += xv.w * w4.z;
      a3.x += xv.x * w4.w; a3.y += xv.y * w4.w; a3.z += xv.z * w4.w; a3.w += xv.w * w4.w;
    }

  const int j0 = jq * 4 + wv;
  float* ob = out + ((size_t)b * C + ch0) * 6400 + i0 * 160 + j0 * 4;
  *(float4*)&ob[0]     = make_float4(a0.x, a1.x, a2.x, a3.x);
  *(float4*)&ob[6400]  = make_float4(a0.y, a1.y, a2.y, a3.y);
  *(float4*)&ob[12800] = make_float4(a0.z, a1.z, a2.z, a3.z);
  *(float4*)&ob[19200] = make_float4(a0.w, a1.w, a2.w, a3.w);
}

// ---------------------------------------------------------------------------
extern "C" void kernel_launch(void* const* d_in, const int* in_sizes, int n_in,
                              void* d_out, int out_size, void* d_ws, size_t ws_size,
                              hipStream_t stream) {
  const float* x      = (const float*)d_in[0];
  const float* w_comp = (const float*)d_in[1];
  const float* w_enc  = (const float*)d_in[2];
  float* out = (float*)d_out;

  float* pc    = (float*)d_ws;                       // 3,276,800 B
  float* encP  = (float*)((char*)d_ws + 3276800);    // 5,120,000 B
  float* wT    = (float*)((char*)d_ws + 8396800);    //   294,912 B
  float* xpad  = (float*)((char*)d_ws + 8691712);    // 4,325,376 B
  float* wnorm = (float*)((char*)d_ws + 13017088);   // 1,280,000 B

  k0_prep<<<dim3(737), 256, 0, stream>>>(x, w_enc, xpad, wT);
  k1_conv1x1<<<dim3(25, 4, B), 256, 0, stream>>>(x, w_comp, pc);
  k2_conv3x3<<<dim3(50, 4, 4), 256, 0, stream>>>(pc, wT, encP);
  k2b_softmax<<<dim3(40, 2), 192, 0, stream>>>(encP, wnorm);
  k3_reassemble<<<dim3(40, 10, B), 256, 0, stream>>>(xpad, wnorm, out);
}

// Round 3
// 103.864 us; speedup vs baseline: 1.2547x; 1.2511x over previous
//
#include <hip/hip_runtime.h>

#define B   2
#define C   256
#define CM  64     // compressed channels
#define CE  100    // encoder out channels
#define H   40
#define W   40
#define HW  1600
#define KK  25     // K*K

// ---------------------------------------------------------------------------
// K1 (fused prep + 1x1 conv), one launch, 937 blocks:
//   blocks   0..199 : 1x1 conv 256->64 LDS GEMM (25 px-tiles, 4 K-quarters, 2 b)
//   blocks 200..711 : zero-pad x -> xpad[b][c][44][48]
//   blocks 712..936 : transpose w_enc -> wT[((ocq*4+icq)*16+icl)*9+tap][32]
// ---------------------------------------------------------------------------
__global__ __launch_bounds__(256) void k1_fused(
    const float* __restrict__ x, const float* __restrict__ w_comp,
    const float* __restrict__ w_enc, float* __restrict__ pc,
    float* __restrict__ xpad, float* __restrict__ wT) {
  const int bid = blockIdx.x;
  const int tid = threadIdx.x;

  if (bid >= 712) {                      // ---- weight transpose (57600 elems)
    int idx = (bid - 712) * 256 + tid;
    if (idx < 57600) {
      int row = idx / 576, col = idx - row * 576;  // col = (icq*16+icl)*9+tap
      int ocq = row / 25, ol = row - ocq * 25;
      wT[((size_t)(ocq * 576 + col)) * 32 + ol] = w_enc[idx];
    }
    return;
  }
  if (bid >= 200) {                      // ---- pad one (b,c) plane of x
    const int plane = bid - 200;         // 0..511
    const float* src = x + (size_t)plane * HW;
    float* dst = xpad + (size_t)plane * (44 * 48);
    for (int i = tid; i < 44 * 48; i += 256) {
      int py = i / 48, px = i - py * 48;
      int gy = py - 2, gx = px - 2;
      float v = 0.f;
      if (gy >= 0 && gy < H && gx >= 0 && gx < W) v = src[gy * W + gx];
      dst[i] = v;
    }
    return;
  }

  // ---- 1x1 conv GEMM (identical to proven k1)
  const int t = bid % 25, ich = (bid / 25) & 3, b = bid / 100;
  __shared__ __align__(16) float xs[64 * 64];    // 16 KB [icl][px]
  __shared__ __align__(16) float wsA[64 * 64];   // 16 KB [icl][oc]

  const float4* x4 = (const float4*)(x + ((size_t)b * C + ich * 64) * HW + t * 64);
#pragma unroll
  for (int i = 0; i < 4; i++) {
    int idx = tid + i * 256;                     // icl = idx>>4, q = idx&15
    ((float4*)xs)[idx] = x4[(idx >> 4) * 400 + (idx & 15)];
  }
  const float4* w4 = (const float4*)w_comp;
#pragma unroll
  for (int i = 0; i < 4; i++) {
    int idx = tid + i * 256;
    int icq = idx >> 6, oc = idx & 63;           // icq 0..15
    float4 f = w4[oc * 64 + ich * 16 + icq];
    wsA[(icq * 4 + 0) * 64 + oc] = f.x;
    wsA[(icq * 4 + 1) * 64 + oc] = f.y;
    wsA[(icq * 4 + 2) * 64 + oc] = f.z;
    wsA[(icq * 4 + 3) * 64 + oc] = f.w;
  }
  __syncthreads();

  const int ty = tid >> 4, tx = tid & 15;
  float acc[4][4];
#pragma unroll
  for (int i = 0; i < 4; i++)
#pragma unroll
    for (int j = 0; j < 4; j++) acc[i][j] = 0.f;

#pragma unroll 4
  for (int icl = 0; icl < 64; icl++) {
    float4 a = *(const float4*)&wsA[icl * 64 + ty * 4];
    float4 bb = *(const float4*)&xs[icl * 64 + tx * 4];
    float av[4] = {a.x, a.y, a.z, a.w};
    float bv[4] = {bb.x, bb.y, bb.z, bb.w};
#pragma unroll
    for (int i = 0; i < 4; i++)
#pragma unroll
      for (int j = 0; j < 4; j++) acc[i][j] += av[i] * bv[j];
  }

  float* o = pc + ((size_t)ich * B + b) * CM * HW + t * 64 + tx * 4;
#pragma unroll
  for (int j = 0; j < 4; j++)
    *(float4*)&o[(size_t)(ty * 4 + j) * HW] =
        make_float4(acc[j][0], acc[j][1], acc[j][2], acc[j][3]);
}

// ---------------------------------------------------------------------------
// K2: 3x3 conv 64 -> 100, pad 1.  grid (50 tiles of 8x4 px, 4 ocq, 4 icq)
// = 800 blocks. Lane = (bb, 8x4 px); 4 waves k-split 16 ic (4 each).
// Weights via wave-uniform scalar loads from wT -> LDS inner loop is a
// single ds_read_b32 per tap. Cross-wave tree-reduce via aliased LDS.
// (Unchanged from round 2 — proven fast.)
// ---------------------------------------------------------------------------
__global__ __launch_bounds__(256) void k2_conv3x3(
    const float* __restrict__ pc, const float* __restrict__ wT,
    float* __restrict__ encP) {
  const int t = blockIdx.x, ocq = blockIdx.y, icq = blockIdx.z;
  const int ty = t / 10, tx = t - ty * 10;       // tile origin (ty*8, tx*4)
  __shared__ __align__(16) float smem[3200];     // 12.8 KB
  float* cs   = smem;    // [bb2][icl16][10*6 halo] = 1920 floats
  float* pacc = smem;    // alias for reduction (3200 floats)
  const int tid = threadIdx.x;

  for (int i = tid; i < 1920; i += 256) {
    int bb = i / 960, r = i - bb * 960;
    int icl = r / 60, rr = r - icl * 60;
    int yy = rr / 6, xx = rr - yy * 6;
    int gy = ty * 8 + yy - 1, gx = tx * 4 + xx - 1;
    float v = 0.f;
    if (gy >= 0 && gy < H && gx >= 0 && gx < W) {
      int o = bb * 102400 + (icq * 16 + icl) * HW + gy * W + gx;
      v = pc[o] + pc[204800 + o] + pc[409600 + o] + pc[614400 + o];
    }
    cs[i] = v;
  }
  __syncthreads();

  const int wv = tid >> 6, lane = tid & 63;
  const int bb = lane >> 5, py = (lane & 31) >> 2, px = lane & 3;
  float acc[25];
#pragma unroll
  for (int j = 0; j < 25; j++) acc[j] = 0.f;

  const float* wbase0 = wT + (size_t)((ocq * 4 + icq) * 16) * 288;  // *9*32

#pragma unroll
  for (int t4 = 0; t4 < 4; t4++) {
    const int icl = __builtin_amdgcn_readfirstlane(wv * 4 + t4);
    const float* c0 = &cs[(bb * 16 + icl) * 60 + py * 6 + px];
    const float* wrow = wbase0 + icl * 288;
#pragma unroll
    for (int dy = 0; dy < 3; dy++)
#pragma unroll
      for (int dx = 0; dx < 3; dx++) {
        const float xv = c0[dy * 6 + dx];
        const float* wq = wrow + (dy * 3 + dx) * 32;
#pragma unroll
        for (int j = 0; j < 25; j++) acc[j] = fmaf(xv, wq[j], acc[j]);
      }
  }

  __syncthreads();
  if (wv == 1 || wv == 3) {
    const int slot = wv >> 1;
#pragma unroll
    for (int j = 0; j < 25; j++) pacc[(slot * 25 + j) * 64 + lane] = acc[j];
  }
  __syncthreads();
  if (wv == 0 || wv == 2) {
    const int slot = wv >> 1;
#pragma unroll
    for (int j = 0; j < 25; j++) acc[j] += pacc[(slot * 25 + j) * 64 + lane];
  }
  __syncthreads();
  if (wv == 2) {
#pragma unroll
    for (int j = 0; j < 25; j++) pacc[j * 64 + lane] = acc[j];
  }
  __syncthreads();
  if (wv == 0) {
    const int base_px = (ty * 8 + py) * W + tx * 4 + px;
#pragma unroll
    for (int ol = 0; ol < 25; ol++)
      encP[(((size_t)icq * 2 + bb) * CE + ocq * 25 + ol) * HW + base_px] =
          acc[ol] + pacc[ol * 64 + lane];
  }
}

// ---------------------------------------------------------------------------
// K3 (fused softmax + reassembly). grid (40 i0, 10 jq, 2 b) = 800 blocks.
// Phase a: 200 threads coalesced-load the 400 (variant,k) encP sums -> sv.
// Phase b: all threads stage x halo from xpad (float4, conflict-free scatter).
// Phase d: 16 threads finish softmax (max/exp/norm, all LDS) -> wlds.
// Phase f: per tap one b128 x-read + one b128 w-broadcast -> 16 FMAs.
// ---------------------------------------------------------------------------
__global__ __launch_bounds__(256) void k3_fused(
    const float* __restrict__ xpad, const float* __restrict__ encP,
    float* __restrict__ out) {
  const int i0 = blockIdx.x;
  const int jq = blockIdx.y;
  const int b  = blockIdx.z;
  const int tid = threadIdx.x;

  __shared__ __align__(16) float xsm[40 * 260];  // 40.6 KB
  __shared__ __align__(16) float sv[400];        // raw logits [k*16 + v]
  __shared__ __align__(16) float wlds[400];      // normalized [j0l*100+k*4+d]

  // ---- (a) softmax partial sums, coalesced (2 (variant,k) pairs per thread)
  const int t20 = (jq >= 5) ? 1 : 0;
  if (tid < 200) {
    const float* eb = encP + (size_t)b * 160000 + i0 * 40;
#pragma unroll
    for (int u = 0; u < 2; u++) {
      const int p = tid * 2 + u;                 // p = k*16 + v
      const int k = p >> 4, v = p & 15;
      const int j0l = v >> 2, d = v & 3;
      const int off = 2 * t20 + (d & 1);
      const int col = (jq * 4 + j0l - 20 * t20) * 2 + (d >> 1);
      const float* ep = eb + (size_t)(k * 4 + off) * 1600 + col;
      sv[p] = ep[0] + ep[320000] + ep[640000] + ep[960000];
    }
  }

  // ---- (b) x halo: 5 rows x 8 cols x 256 ch from padded x
  {
    const float* xb = xpad + (size_t)b * 256 * (44 * 48) + i0 * 48 + jq * 4;
    const int f4 = tid & 1, cth = tid >> 1;      // cth 0..127
#pragma unroll
    for (int it = 0; it < 10; it++) {
      const int ki = (it < 5) ? it : it - 5;
      const int c  = (it < 5 ? 0 : 128) + cth;
      float4 v = *(const float4*)(xb + ((size_t)c * 44 + ki) * 48 + f4 * 4);
      const int px = ki * 8 + f4 * 4;
      xsm[(px + 0) * 260 + c] = v.x;
      xsm[(px + 1) * 260 + c] = v.y;
      xsm[(px + 2) * 260 + c] = v.z;
      xsm[(px + 3) * 260 + c] = v.w;
    }
  }
  __syncthreads();

  // ---- (d) finish softmax: 16 threads, one (j0l,d) variant each, all in LDS
  if (tid < 16) {
    const int j0l = tid >> 2, d = tid & 3;
    float vk[KK];
    float m = -1e30f;
#pragma unroll
    for (int k = 0; k < KK; k++) {
      vk[k] = sv[k * 16 + tid];
      m = fmaxf(m, vk[k]);
    }
    float s = 0.f;
#pragma unroll
    for (int k = 0; k < KK; k++) {
      vk[k] = expf(vk[k] - m);
      s += vk[k];
    }
    const float inv = 1.f / s;
#pragma unroll
    for (int k = 0; k < KK; k++) wlds[j0l * 100 + k * 4 + d] = vk[k] * inv;
  }
  __syncthreads();

  // ---- (f) reassembly compute
  const int wv = tid >> 6, lane = tid & 63, ch0 = lane * 4;
  float4 a0 = make_float4(0.f, 0.f, 0.f, 0.f);
  float4 a1 = a0, a2 = a0, a3 = a0;

#pragma unroll
  for (int ki = 0; ki < 5; ki++)
#pragma unroll
    for (int kj = 0; kj < 5; kj++) {
      float4 xv = *(const float4*)&xsm[(ki * 8 + wv + kj) * 260 + ch0];
      float4 w4 = *(const float4*)&wlds[wv * 100 + (ki * 5 + kj) * 4];
      a0.x += xv.x * w4.x; a0.y += xv.y * w4.x; a0.z += xv.z * w4.x; a0.w += xv.w * w4.x;
      a1.x += xv.x * w4.y; a1.y += xv.y * w4.y; a1.z += xv.z * w4.y; a1.w += xv.w * w4.y;
      a2.x += xv.x * w4.z; a2.y += xv.y * w4.z; a2.z += xv.z * w4.z; a2.w += xv.w * w4.z;
      a3.x += xv.x * w4.w; a3.y += xv.y * w4.w; a3.z += xv.z * w4.w; a3.w += xv.w * w4.w;
    }

  const int j0 = jq * 4 + wv;
  float* ob = out + ((size_t)b * C + ch0) * 6400 + i0 * 160 + j0 * 4;
  *(float4*)&ob[0]     = make_float4(a0.x, a1.x, a2.x, a3.x);
  *(float4*)&ob[6400]  = make_float4(a0.y, a1.y, a2.y, a3.y);
  *(float4*)&ob[12800] = make_float4(a0.z, a1.z, a2.z, a3.z);
  *(float4*)&ob[19200] = make_float4(a0.w, a1.w, a2.w, a3.w);
}

// ---------------------------------------------------------------------------
extern "C" void kernel_launch(void* const* d_in, const int* in_sizes, int n_in,
                              void* d_out, int out_size, void* d_ws, size_t ws_size,
                              hipStream_t stream) {
  const float* x      = (const float*)d_in[0];
  const float* w_comp = (const float*)d_in[1];
  const float* w_enc  = (const float*)d_in[2];
  float* out = (float*)d_out;

  float* pc    = (float*)d_ws;                       // 3,276,800 B
  float* encP  = (float*)((char*)d_ws + 3276800);    // 5,120,000 B
  float* wT    = (float*)((char*)d_ws + 8396800);    //   294,912 B
  float* xpad  = (float*)((char*)d_ws + 8691712);    // 4,325,376 B

  k1_fused<<<dim3(937), 256, 0, stream>>>(x, w_comp, w_enc, pc, xpad, wT);
  k2_conv3x3<<<dim3(50, 4, 4), 256, 0, stream>>>(pc, wT, encP);
  k3_fused<<<dim3(40, 10, B), 256, 0, stream>>>(xpad, encP, out);
}